// Round 1
// baseline (1582.224 us; speedup 1.0000x reference)
//
#include <hip/hip_runtime.h>

#define BB_ 4
#define TT_ 8
#define CC_ 64
#define HW 4096
#define UMAP 1024      // floats per (b,c) spectrum map: 32 ky * 16 kx * 2
#define STEP 0.09817477042468103f   // 2*pi/64

// ws float offsets
#define OFF_UX   0
#define OFF_UH   (OFF_UX + BB_*CC_*UMAP)
#define OFF_URH  (OFF_UH + BB_*CC_*UMAP)
#define OFF_SPART (OFF_URH + BB_*CC_*UMAP)          // 2*4*B*C*UMAP floats
#define OFF_H    (OFF_SPART + 2*4*BB_*CC_*UMAP)
#define OFF_Z    (OFF_H + BB_*CC_*HW)
#define OFF_RH   (OFF_Z + BB_*CC_*HW)
#define OFF_PH   (OFF_RH + BB_*CC_*HW)

__global__ __launch_bounds__(256) void k_init_h(float* __restrict__ h,
                                                const float* __restrict__ bias_h) {
    float v = bias_h[0];
    int idx = (blockIdx.x * 256 + threadIdx.x) * 4;
    *(float4*)(h + idx) = make_float4(v, v, v, v);
}

// Forward partial DFT of one 64x64 map per block.
// Output layout per (b,c): [ky_idx 0..31][kx 0..15][re,im], ky = ky_idx<16 ? ky_idx : ky_idx+32
__global__ __launch_bounds__(256) void k_fwd_dft2(
    const float* __restrict__ srcA, long long bsA, float* __restrict__ dstA,
    const float* __restrict__ srcB, long long bsB, float* __restrict__ dstB)
{
    __shared__ float su[64 * 65];
    __shared__ float FxR[64 * 16];
    __shared__ float FxI[64 * 16];
    int which = blockIdx.x >> 8;
    int map = blockIdx.x & 255;
    int b = map >> 6, c = map & 63;
    const float* src = (which ? srcB : srcA) + (long long)b * (which ? bsB : bsA) + c * HW;
    float* dst = (which ? dstB : dstA) + map * UMAP;
    int tid = threadIdx.x;
    #pragma unroll
    for (int k = 0; k < 4; k++) {
        int off = k * 1024 + tid * 4;
        float4 v = *(const float4*)(src + off);
        int y = off >> 6, x = off & 63;
        su[y * 65 + x + 0] = v.x; su[y * 65 + x + 1] = v.y;
        su[y * 65 + x + 2] = v.z; su[y * 65 + x + 3] = v.w;
    }
    __syncthreads();
    // stage 1: along x. thread -> fixed kx = tid&15, 4 y's
    int kx = tid & 15, yb = tid >> 4;
    float stc, sts;
    __sincosf(-STEP * (float)kx, &sts, &stc);
    float wr = 1.f, wi = 0.f;
    float aR[4] = {0, 0, 0, 0}, aI[4] = {0, 0, 0, 0};
    for (int x = 0; x < 64; x++) {
        #pragma unroll
        for (int j = 0; j < 4; j++) {
            float v = su[(yb + 16 * j) * 65 + x];
            aR[j] = fmaf(v, wr, aR[j]);
            aI[j] = fmaf(v, wi, aI[j]);
        }
        float t = wr * stc - wi * sts;
        wi = wr * sts + wi * stc;
        wr = t;
    }
    #pragma unroll
    for (int j = 0; j < 4; j++) {
        FxR[(yb + 16 * j) * 16 + kx] = aR[j];
        FxI[(yb + 16 * j) * 16 + kx] = aI[j];
    }
    __syncthreads();
    // stage 2: along y. thread -> fixed kx, two ky (kb and kb+48)
    int kb = tid >> 4;
    float c0, s0, c1, s1;
    __sincosf(-STEP * (float)kb, &s0, &c0);
    __sincosf(-STEP * (float)(kb + 48), &s1, &c1);
    float w0r = 1, w0i = 0, w1r = 1, w1i = 0;
    float A0r = 0, A0i = 0, A1r = 0, A1i = 0;
    for (int y = 0; y < 64; y++) {
        float Fr = FxR[y * 16 + kx], Fi = FxI[y * 16 + kx];
        A0r = fmaf(Fr, w0r, A0r); A0r = fmaf(-Fi, w0i, A0r);
        A0i = fmaf(Fr, w0i, A0i); A0i = fmaf(Fi, w0r, A0i);
        A1r = fmaf(Fr, w1r, A1r); A1r = fmaf(-Fi, w1i, A1r);
        A1i = fmaf(Fr, w1i, A1i); A1i = fmaf(Fi, w1r, A1i);
        float t0 = w0r * c0 - w0i * s0; w0i = w0r * s0 + w0i * c0; w0r = t0;
        float t1 = w1r * c1 - w1i * s1; w1i = w1r * s1 + w1i * c1; w1r = t1;
    }
    const float sc = 1.f / 64.f;
    float2* d2 = (float2*)dst;
    d2[kb * 16 + kx]        = make_float2(A0r * sc, A0i * sc);
    d2[(kb + 16) * 16 + kx] = make_float2(A1r * sc, A1i * sc);
}

// Per-mode channel mix, partial over i-chunks of 16.
// block: [g(ngates)][half(2)][kyrow(16)][ichunk(4)]  (g = blk>>7)
// thread: o = tid&63, b = tid>>6. Each thread: 16 kx complex accumulators.
// S_g = sum_i UA[b,i,m] * W[lA_g][i,o,m]  +  sum_i UB[b,i,m] * W[lB_g][i,o,m]
__global__ __launch_bounds__(256) void k_mix(
    const float* __restrict__ UA, const float* __restrict__ UB,
    int lA0, int lB0, int lA1, int lB1,
    const float* __restrict__ sw1, const float* __restrict__ sw2,
    float* __restrict__ Spart)
{
    __shared__ float Us[2 * 16 * 4 * 40];   // [p][il][b][32 of 40]
    int blk = blockIdx.x;
    int g = blk >> 7;
    int r = blk & 127;
    int ic = r & 3, kyrow = (r >> 2) & 15, half = r >> 6;
    int kyidx = half * 16 + kyrow;
    int ib = ic * 16;
    int tid = threadIdx.x;
    int o = tid & 63, b = tid >> 6;
    for (int n = 0; n < 16; n++) {
        int idx = n * 256 + tid;
        int p = idx >> 11;
        int il = (idx >> 7) & 15;
        int bb = (idx >> 5) & 3;
        int f = idx & 31;
        const float* up = p ? UB : UA;
        Us[((p * 16 + il) * 4 + bb) * 40 + f] = up[(bb * 64 + ib + il) * UMAP + kyidx * 32 + f];
    }
    __syncthreads();
    float aR[16], aI[16];
    #pragma unroll
    for (int k = 0; k < 16; k++) { aR[k] = 0.f; aI[k] = 0.f; }
    int lA = g ? lA1 : lA0;
    int lB = g ? lB1 : lB0;
    const float* wbase_h = half ? sw2 : sw1;
    #pragma unroll
    for (int p = 0; p < 2; p++) {
        int l = p ? lB : lA;
        const float* wb = wbase_h + (size_t)l * (CC_ * CC_ * 16 * 16 * 2);
        for (int il = 0; il < 16; il++) {
            int i = ib + il;
            const float4* wp = (const float4*)(wb + ((size_t)(i * 64 + o) * 256 + kyrow * 16) * 2);
            const float4* up4 = (const float4*)(&Us[((p * 16 + il) * 4 + b) * 40]);
            #pragma unroll
            for (int q = 0; q < 8; q++) {
                float4 wq = wp[q];
                float4 uq = up4[q];
                int k0 = 2 * q, k1 = 2 * q + 1;
                aR[k0] = fmaf(uq.x, wq.x, aR[k0]); aR[k0] = fmaf(-uq.y, wq.y, aR[k0]);
                aI[k0] = fmaf(uq.x, wq.y, aI[k0]); aI[k0] = fmaf(uq.y, wq.x, aI[k0]);
                aR[k1] = fmaf(uq.z, wq.z, aR[k1]); aR[k1] = fmaf(-uq.w, wq.w, aR[k1]);
                aI[k1] = fmaf(uq.z, wq.w, aI[k1]); aI[k1] = fmaf(uq.w, wq.z, aI[k1]);
            }
        }
    }
    float2* o2 = (float2*)(Spart + ((size_t)((g * 4 + ic) * 4 + b) * 64 + o) * UMAP + kyidx * 32);
    #pragma unroll
    for (int k = 0; k < 16; k++) o2[k] = make_float2(aR[k], aI[k]);
}

// skip (1x1 conv): out_g = sum_i uA[b,i,px]*skw[lA][i,o] + sum_i uB[b,i,px]*skw[lB][i,o] + gb
// block: [g][b(4)][tile(64)]; thread: o = tid&63, wave = tid>>6 handles 16 px.
__global__ __launch_bounds__(256) void k_skip2(
    const float* __restrict__ uA, long long bsA,
    const float* __restrict__ uB, long long bsB,
    const float* __restrict__ skw,
    int lA0, int lB0, int lA1, int lB1,
    const float* __restrict__ gate_b, int g0, int g1,
    float* __restrict__ out0, float* __restrict__ out1)
{
    __shared__ float sA[4096], sB[4096];
    int blk = blockIdx.x;
    int g = blk >> 8;
    int r = blk & 255;
    int b = r >> 6, tile = r & 63;
    int tid = threadIdx.x;
    int o = tid & 63, wv = tid >> 6;
    int pxb = tile * 64 + wv * 16;
    int lA = g ? lA1 : lA0;
    int lB = g ? lB1 : lB0;
    for (int n = 0; n < 16; n++) {
        int idx = n * 256 + tid;
        sA[idx] = skw[lA * 4096 + idx];
        sB[idx] = skw[lB * 4096 + idx];
    }
    __syncthreads();
    float acc[16];
    #pragma unroll
    for (int k = 0; k < 16; k++) acc[k] = 0.f;
    const float* pa = uA + (long long)b * bsA + pxb;
    const float* pb = uB + (long long)b * bsB + pxb;
    for (int i = 0; i < 64; i++) {
        float wa = sA[i * 64 + o];
        float wb2 = sB[i * 64 + o];
        const float4* qa = (const float4*)(pa + i * HW);
        const float4* qb = (const float4*)(pb + i * HW);
        #pragma unroll
        for (int q = 0; q < 4; q++) {
            float4 va = qa[q], vb = qb[q];
            acc[4 * q + 0] = fmaf(wa, va.x, acc[4 * q + 0]);
            acc[4 * q + 0] = fmaf(wb2, vb.x, acc[4 * q + 0]);
            acc[4 * q + 1] = fmaf(wa, va.y, acc[4 * q + 1]);
            acc[4 * q + 1] = fmaf(wb2, vb.y, acc[4 * q + 1]);
            acc[4 * q + 2] = fmaf(wa, va.z, acc[4 * q + 2]);
            acc[4 * q + 2] = fmaf(wb2, vb.z, acc[4 * q + 2]);
            acc[4 * q + 3] = fmaf(wa, va.w, acc[4 * q + 3]);
            acc[4 * q + 3] = fmaf(wb2, vb.w, acc[4 * q + 3]);
        }
    }
    float gb = gate_b[g ? g1 : g0];
    float* outp = (g ? out1 : out0) + ((long long)b * 64 + o) * HW + pxb;
    #pragma unroll
    for (int k = 0; k < 16; k++) outp[k] = acc[k] + gb;
}

// inverse partial DFT per (gate, b, o) map + epilogue activations.
// is_h=0: g=0 -> z = sigmoid(idft + zbuf); g=1 -> rh = sigmoid(idft + rhbuf) * h
// is_h=1: hh = selu(idft + phbuf); h = (1-z)h + z*hh
__global__ __launch_bounds__(256) void k_idft(
    const float* __restrict__ Spart,
    float* __restrict__ zbuf, float* __restrict__ rhbuf,
    float* __restrict__ hbuf, float* __restrict__ phbuf,
    int is_h)
{
    __shared__ float SR[512], SI[512];
    __shared__ float GR[1024], GI[1024];
    int g = is_h ? 0 : (blockIdx.x >> 8);
    int map = blockIdx.x & 255;
    int b = map >> 6, o = map & 63;
    int tid = threadIdx.x;
    {
        const float4* c0 = (const float4*)(Spart + ((size_t)(g * 4 + 0) * 256 + map) * UMAP);
        const float4* c1 = (const float4*)(Spart + ((size_t)(g * 4 + 1) * 256 + map) * UMAP);
        const float4* c2 = (const float4*)(Spart + ((size_t)(g * 4 + 2) * 256 + map) * UMAP);
        const float4* c3 = (const float4*)(Spart + ((size_t)(g * 4 + 3) * 256 + map) * UMAP);
        float4 v0 = c0[tid], v1 = c1[tid], v2 = c2[tid], v3 = c3[tid];
        float sxr = v0.x + v1.x + v2.x + v3.x;
        float sxi = v0.y + v1.y + v2.y + v3.y;
        float syr = v0.z + v1.z + v2.z + v3.z;
        float syi = v0.w + v1.w + v2.w + v3.w;
        SR[2 * tid] = sxr; SI[2 * tid] = sxi;
        SR[2 * tid + 1] = syr; SI[2 * tid + 1] = syi;
    }
    __syncthreads();
    // stage 1: over ky. thread: fixed kx = tid&15, 4 y's
    int kx = tid & 15, yb = tid >> 4;
    #pragma unroll
    for (int j = 0; j < 4; j++) {
        int y = yb + 16 * j;
        float stc, sts;
        __sincosf(STEP * (float)y, &sts, &stc);
        float ar = 0.f, ai = 0.f;
        float wr = 1.f, wi = 0.f;
        for (int k = 0; k < 16; k++) {
            float sr_ = SR[k * 16 + kx], si_ = SI[k * 16 + kx];
            ar = fmaf(sr_, wr, ar); ar = fmaf(-si_, wi, ar);
            ai = fmaf(sr_, wi, ai); ai = fmaf(si_, wr, ai);
            float t = wr * stc - wi * sts; wi = wr * sts + wi * stc; wr = t;
        }
        // bottom run: ky = 48..63, start phase e^{2pi*i*48*y/64} = i^{(3y) mod 4} (exact)
        int q = (3 * y) & 3;
        float w2r = (q == 0) ? 1.f : ((q == 2) ? -1.f : 0.f);
        float w2i = (q == 1) ? 1.f : ((q == 3) ? -1.f : 0.f);
        for (int k = 16; k < 32; k++) {
            float sr_ = SR[k * 16 + kx], si_ = SI[k * 16 + kx];
            ar = fmaf(sr_, w2r, ar); ar = fmaf(-si_, w2i, ar);
            ai = fmaf(sr_, w2i, ai); ai = fmaf(si_, w2r, ai);
            float t = w2r * stc - w2i * sts; w2i = w2r * sts + w2i * stc; w2r = t;
        }
        GR[y * 16 + kx] = ar;
        GI[y * 16 + kx] = ai;
    }
    __syncthreads();
    // stage 2: over kx with c_kx weights (c2r semantics), + epilogue
    int x = tid & 63, ybase = tid >> 6;
    float cx, sx;
    __sincosf(STEP * (float)x, &sx, &cx);
    size_t mo = ((size_t)b * 64 + o) * HW;
    #pragma unroll
    for (int j = 0; j < 16; j++) {
        int y = ybase + 4 * j;
        float acc = GR[y * 16];   // kx = 0 term, weight 1, take Re
        float wr = cx, wi = sx;
        #pragma unroll
        for (int k = 1; k < 16; k++) {
            acc = fmaf(2.f * GR[y * 16 + k], wr, acc);
            acc = fmaf(-2.f * GI[y * 16 + k], wi, acc);
            float t = wr * cx - wi * sx; wi = wr * sx + wi * cx; wr = t;
        }
        float val = acc * (1.f / 64.f);
        int idx = y * 64 + x;
        if (is_h) {
            float pre = val + phbuf[mo + idx];
            float hh = (pre > 0.f) ? 1.0507009873554805f * pre
                                   : 1.7580993408473766f * (__expf(pre) - 1.f); // scale*alpha
            float z = zbuf[mo + idx];
            float hold = hbuf[mo + idx];
            hbuf[mo + idx] = (1.f - z) * hold + z * hh;
        } else if (g == 0) {
            float pre = val + zbuf[mo + idx];
            zbuf[mo + idx] = 1.f / (1.f + __expf(-pre));
        } else {
            float pre = val + rhbuf[mo + idx];
            float rr = 1.f / (1.f + __expf(-pre));
            rhbuf[mo + idx] = rr * hbuf[mo + idx];
        }
    }
}

extern "C" void kernel_launch(void* const* d_in, const int* in_sizes, int n_in,
                              void* d_out, int out_size, void* d_ws, size_t ws_size,
                              hipStream_t stream)
{
    (void)in_sizes; (void)n_in; (void)out_size; (void)ws_size;
    const float* x   = (const float*)d_in[0];
    const float* sw1 = (const float*)d_in[1];
    const float* sw2 = (const float*)d_in[2];
    const float* skw = (const float*)d_in[3];
    const float* gb  = (const float*)d_in[4];
    const float* bh  = (const float*)d_in[5];
    float* ws  = (float*)d_ws;
    float* Ux  = ws + OFF_UX;
    float* Uh  = ws + OFF_UH;
    float* Urh = ws + OFF_URH;
    float* Sp  = ws + OFF_SPART;
    float* hb  = ws + OFF_H;
    float* zb  = ws + OFF_Z;
    float* rhb = ws + OFF_RH;
    float* phb = ws + OFF_PH;

    const long long bs_x = (long long)TT_ * CC_ * HW;  // b-stride within x
    const long long bs_h = (long long)CC_ * HW;

    k_init_h<<<1024, 256, 0, stream>>>(hb, bh);
    for (int t = 0; t < TT_; t++) {
        const float* xt = x + (size_t)t * CC_ * HW;
        // spectra of xt and h
        k_fwd_dft2<<<512, 256, 0, stream>>>(xt, bs_x, Ux, hb, bs_h, Uh);
        // z & r spectral mixes (layers 0,1 and 2,3), i-chunk partials
        k_mix<<<256, 256, 0, stream>>>(Ux, Uh, 0, 1, 2, 3, sw1, sw2, Sp);
        // z & r skips + gate bias -> preactivations in zb / rhb
        k_skip2<<<512, 256, 0, stream>>>(xt, bs_x, hb, bs_h, skw,
                                         0, 1, 2, 3, gb, 0, 1, zb, rhb);
        // z = sigmoid(.), rh = sigmoid(.)*h
        k_idft<<<512, 256, 0, stream>>>(Sp, zb, rhb, hb, phb, 0);
        // spectrum of r*h
        k_fwd_dft2<<<256, 256, 0, stream>>>(rhb, bs_h, Urh, rhb, bs_h, Urh);
        // h_hat spectral mix (layers 4,5)
        k_mix<<<128, 256, 0, stream>>>(Ux, Urh, 4, 5, 4, 5, sw1, sw2, Sp);
        // h_hat skip -> phb
        k_skip2<<<256, 256, 0, stream>>>(xt, bs_x, rhb, bs_h, skw,
                                         4, 5, 4, 5, gb, 2, 2, phb, phb);
        // h = (1-z)h + z*selu(.)
        k_idft<<<256, 256, 0, stream>>>(Sp, zb, rhb, hb, phb, 1);
    }
    hipMemcpyAsync(d_out, hb, (size_t)BB_ * CC_ * HW * sizeof(float),
                   hipMemcpyDeviceToDevice, stream);
}

// Round 2
// 1231.669 us; speedup vs baseline: 1.2846x; 1.2846x over previous
//
#include <hip/hip_runtime.h>

#define BB_ 4
#define TT_ 8
#define CC_ 64
#define HW 4096
#define UMAP 1024      // floats per (b,c) spectrum map: 32 ky * 16 kx * 2
#define STEP 0.09817477042468103f   // 2*pi/64

// ws float offsets
#define OFF_UX   0
#define OFF_UH   (OFF_UX + BB_*CC_*UMAP)
#define OFF_URH  (OFF_UH + BB_*CC_*UMAP)
#define OFF_SPART (OFF_URH + BB_*CC_*UMAP)          // 2*4*B*C*UMAP floats
#define OFF_H    (OFF_SPART + 2*4*BB_*CC_*UMAP)
#define OFF_Z    (OFF_H + BB_*CC_*HW)
#define OFF_RH   (OFF_Z + BB_*CC_*HW)
#define OFF_PH   (OFF_RH + BB_*CC_*HW)

__global__ __launch_bounds__(256) void k_init_h(float* __restrict__ h,
                                                const float* __restrict__ bias_h) {
    float v = bias_h[0];
    int idx = (blockIdx.x * 256 + threadIdx.x) * 4;
    *(float4*)(h + idx) = make_float4(v, v, v, v);
}

// Forward partial DFT of one 64x64 map per block.
// Output layout per (b,c): [ky_idx 0..31][kx 0..15][re,im], ky = ky_idx<16 ? ky_idx : ky_idx+32
__global__ __launch_bounds__(256) void k_fwd_dft2(
    const float* __restrict__ srcA, long long bsA, float* __restrict__ dstA,
    const float* __restrict__ srcB, long long bsB, float* __restrict__ dstB)
{
    __shared__ float su[64 * 65];
    __shared__ float FxR[64 * 16];
    __shared__ float FxI[64 * 16];
    int which = blockIdx.x >> 8;
    int map = blockIdx.x & 255;
    int b = map >> 6, c = map & 63;
    const float* src = (which ? srcB : srcA) + (long long)b * (which ? bsB : bsA) + c * HW;
    float* dst = (which ? dstB : dstA) + map * UMAP;
    int tid = threadIdx.x;
    #pragma unroll
    for (int k = 0; k < 4; k++) {
        int off = k * 1024 + tid * 4;
        float4 v = *(const float4*)(src + off);
        int y = off >> 6, x = off & 63;
        su[y * 65 + x + 0] = v.x; su[y * 65 + x + 1] = v.y;
        su[y * 65 + x + 2] = v.z; su[y * 65 + x + 3] = v.w;
    }
    __syncthreads();
    // stage 1: along x. thread -> fixed kx = tid&15, 4 y's
    int kx = tid & 15, yb = tid >> 4;
    float stc, sts;
    __sincosf(-STEP * (float)kx, &sts, &stc);
    float wr = 1.f, wi = 0.f;
    float aR[4] = {0, 0, 0, 0}, aI[4] = {0, 0, 0, 0};
    for (int x = 0; x < 64; x++) {
        #pragma unroll
        for (int j = 0; j < 4; j++) {
            float v = su[(yb + 16 * j) * 65 + x];
            aR[j] = fmaf(v, wr, aR[j]);
            aI[j] = fmaf(v, wi, aI[j]);
        }
        float t = wr * stc - wi * sts;
        wi = wr * sts + wi * stc;
        wr = t;
    }
    #pragma unroll
    for (int j = 0; j < 4; j++) {
        FxR[(yb + 16 * j) * 16 + kx] = aR[j];
        FxI[(yb + 16 * j) * 16 + kx] = aI[j];
    }
    __syncthreads();
    // stage 2: along y. thread -> fixed kx, two ky (kb and kb+48)
    int kb = tid >> 4;
    float c0, s0, c1, s1;
    __sincosf(-STEP * (float)kb, &s0, &c0);
    __sincosf(-STEP * (float)(kb + 48), &s1, &c1);
    float w0r = 1, w0i = 0, w1r = 1, w1i = 0;
    float A0r = 0, A0i = 0, A1r = 0, A1i = 0;
    for (int y = 0; y < 64; y++) {
        float Fr = FxR[y * 16 + kx], Fi = FxI[y * 16 + kx];
        A0r = fmaf(Fr, w0r, A0r); A0r = fmaf(-Fi, w0i, A0r);
        A0i = fmaf(Fr, w0i, A0i); A0i = fmaf(Fi, w0r, A0i);
        A1r = fmaf(Fr, w1r, A1r); A1r = fmaf(-Fi, w1i, A1r);
        A1i = fmaf(Fr, w1i, A1i); A1i = fmaf(Fi, w1r, A1i);
        float t0 = w0r * c0 - w0i * s0; w0i = w0r * s0 + w0i * c0; w0r = t0;
        float t1 = w1r * c1 - w1i * s1; w1i = w1r * s1 + w1i * c1; w1r = t1;
    }
    const float sc = 1.f / 64.f;
    float2* d2 = (float2*)dst;
    d2[kb * 16 + kx]        = make_float2(A0r * sc, A0i * sc);
    d2[(kb + 16) * 16 + kx] = make_float2(A1r * sc, A1i * sc);
}

// Per-mode channel mix v2: lanes <-> modes (coalesced weight stream).
// block bits: [g][half][ic(4)][og(32)]; thread m = mode within half (256).
// Each thread: o-pair {2*og, 2*og+1} x 4 b complex accumulators.
// S_g = sum_i UA[b,i,m] * W[lA_g][i,o,m]  +  sum_i UB[b,i,m] * W[lB_g][i,o,m]
// Spart layout (unchanged from v1): [((g*4+ic)*4+b)*64+o][UMAP], partials over ic.
__global__ __launch_bounds__(256) void k_mix(
    const float* __restrict__ UA, const float* __restrict__ UB,
    int lA0, int lB0, int lA1, int lB1,
    const float* __restrict__ sw1, const float* __restrict__ sw2,
    float* __restrict__ Spart)
{
    int blk = blockIdx.x;
    int og = blk & 31;
    int ic = (blk >> 5) & 3;
    int half = (blk >> 7) & 1;
    int g = blk >> 8;
    int m = threadIdx.x;
    int o0 = og * 2;
    int ib = ic * 16;
    const float* wbase = half ? sw2 : sw1;
    int lA = g ? lA1 : lA0;
    int lB = g ? lB1 : lB0;
    float a0R[4], a0I[4], a1R[4], a1I[4];
    #pragma unroll
    for (int b = 0; b < 4; b++) { a0R[b] = 0.f; a0I[b] = 0.f; a1R[b] = 0.f; a1I[b] = 0.f; }
    #pragma unroll
    for (int p = 0; p < 2; p++) {
        const float* U = p ? UB : UA;
        const float* wl = wbase + (size_t)(p ? lB : lA) * (CC_ * CC_ * 512);
        const float2* w0p = (const float2*)wl + ((size_t)(ib * 64 + o0) * 256 + m);
        const float2* Ub  = (const float2*)U + ((size_t)ib * 512 + half * 256 + m);
        for (int i = 0; i < 16; i++) {
            float2 w0 = w0p[(size_t)i * 16384];
            float2 w1 = w0p[(size_t)i * 16384 + 256];
            #pragma unroll
            for (int b = 0; b < 4; b++) {
                float2 u = Ub[(size_t)(b * 64 + i) * 512];
                a0R[b] = fmaf(u.x, w0.x, a0R[b]); a0R[b] = fmaf(-u.y, w0.y, a0R[b]);
                a0I[b] = fmaf(u.x, w0.y, a0I[b]); a0I[b] = fmaf(u.y, w0.x, a0I[b]);
                a1R[b] = fmaf(u.x, w1.x, a1R[b]); a1R[b] = fmaf(-u.y, w1.y, a1R[b]);
                a1I[b] = fmaf(u.x, w1.y, a1I[b]); a1I[b] = fmaf(u.y, w1.x, a1I[b]);
            }
        }
    }
    #pragma unroll
    for (int b = 0; b < 4; b++) {
        float2* d = (float2*)Spart + ((size_t)((g * 4 + ic) * 4 + b) * 64) * 512;
        d[(size_t)o0 * 512 + half * 256 + m]       = make_float2(a0R[b], a0I[b]);
        d[(size_t)(o0 + 1) * 512 + half * 256 + m] = make_float2(a1R[b], a1I[b]);
    }
}

// skip (1x1 conv): out_g = sum_i uA[b,i,px]*skw[lA][i,o] + sum_i uB[b,i,px]*skw[lB][i,o] + gb
// block: [g][b(4)][tile(64)]; thread: o = tid&63, wave = tid>>6 handles 16 px.
__global__ __launch_bounds__(256) void k_skip2(
    const float* __restrict__ uA, long long bsA,
    const float* __restrict__ uB, long long bsB,
    const float* __restrict__ skw,
    int lA0, int lB0, int lA1, int lB1,
    const float* __restrict__ gate_b, int g0, int g1,
    float* __restrict__ out0, float* __restrict__ out1)
{
    __shared__ float sA[4096], sB[4096];
    int blk = blockIdx.x;
    int g = blk >> 8;
    int r = blk & 255;
    int b = r >> 6, tile = r & 63;
    int tid = threadIdx.x;
    int o = tid & 63, wv = tid >> 6;
    int pxb = tile * 64 + wv * 16;
    int lA = g ? lA1 : lA0;
    int lB = g ? lB1 : lB0;
    for (int n = 0; n < 16; n++) {
        int idx = n * 256 + tid;
        sA[idx] = skw[lA * 4096 + idx];
        sB[idx] = skw[lB * 4096 + idx];
    }
    __syncthreads();
    float acc[16];
    #pragma unroll
    for (int k = 0; k < 16; k++) acc[k] = 0.f;
    const float* pa = uA + (long long)b * bsA + pxb;
    const float* pb = uB + (long long)b * bsB + pxb;
    for (int i = 0; i < 64; i++) {
        float wa = sA[i * 64 + o];
        float wb2 = sB[i * 64 + o];
        const float4* qa = (const float4*)(pa + i * HW);
        const float4* qb = (const float4*)(pb + i * HW);
        #pragma unroll
        for (int q = 0; q < 4; q++) {
            float4 va = qa[q], vb = qb[q];
            acc[4 * q + 0] = fmaf(wa, va.x, acc[4 * q + 0]);
            acc[4 * q + 0] = fmaf(wb2, vb.x, acc[4 * q + 0]);
            acc[4 * q + 1] = fmaf(wa, va.y, acc[4 * q + 1]);
            acc[4 * q + 1] = fmaf(wb2, vb.y, acc[4 * q + 1]);
            acc[4 * q + 2] = fmaf(wa, va.z, acc[4 * q + 2]);
            acc[4 * q + 2] = fmaf(wb2, vb.z, acc[4 * q + 2]);
            acc[4 * q + 3] = fmaf(wa, va.w, acc[4 * q + 3]);
            acc[4 * q + 3] = fmaf(wb2, vb.w, acc[4 * q + 3]);
        }
    }
    float gb = gate_b[g ? g1 : g0];
    float* outp = (g ? out1 : out0) + ((long long)b * 64 + o) * HW + pxb;
    #pragma unroll
    for (int k = 0; k < 16; k++) outp[k] = acc[k] + gb;
}

// inverse partial DFT per (gate, b, o) map + epilogue activations.
// is_h=0: g=0 -> z = sigmoid(idft + zbuf); g=1 -> rh = sigmoid(idft + rhbuf) * h
// is_h=1: hh = selu(idft + phbuf); h = (1-z)h + z*hh
__global__ __launch_bounds__(256) void k_idft(
    const float* __restrict__ Spart,
    float* __restrict__ zbuf, float* __restrict__ rhbuf,
    float* __restrict__ hbuf, float* __restrict__ phbuf,
    int is_h)
{
    __shared__ float SR[512], SI[512];
    __shared__ float GR[1024], GI[1024];
    int g = is_h ? 0 : (blockIdx.x >> 8);
    int map = blockIdx.x & 255;
    int b = map >> 6, o = map & 63;
    int tid = threadIdx.x;
    {
        const float4* c0 = (const float4*)(Spart + ((size_t)(g * 4 + 0) * 256 + map) * UMAP);
        const float4* c1 = (const float4*)(Spart + ((size_t)(g * 4 + 1) * 256 + map) * UMAP);
        const float4* c2 = (const float4*)(Spart + ((size_t)(g * 4 + 2) * 256 + map) * UMAP);
        const float4* c3 = (const float4*)(Spart + ((size_t)(g * 4 + 3) * 256 + map) * UMAP);
        float4 v0 = c0[tid], v1 = c1[tid], v2 = c2[tid], v3 = c3[tid];
        float sxr = v0.x + v1.x + v2.x + v3.x;
        float sxi = v0.y + v1.y + v2.y + v3.y;
        float syr = v0.z + v1.z + v2.z + v3.z;
        float syi = v0.w + v1.w + v2.w + v3.w;
        SR[2 * tid] = sxr; SI[2 * tid] = sxi;
        SR[2 * tid + 1] = syr; SI[2 * tid + 1] = syi;
    }
    __syncthreads();
    // stage 1: over ky. thread: fixed kx = tid&15, 4 y's
    int kx = tid & 15, yb = tid >> 4;
    #pragma unroll
    for (int j = 0; j < 4; j++) {
        int y = yb + 16 * j;
        float stc, sts;
        __sincosf(STEP * (float)y, &sts, &stc);
        float ar = 0.f, ai = 0.f;
        float wr = 1.f, wi = 0.f;
        for (int k = 0; k < 16; k++) {
            float sr_ = SR[k * 16 + kx], si_ = SI[k * 16 + kx];
            ar = fmaf(sr_, wr, ar); ar = fmaf(-si_, wi, ar);
            ai = fmaf(sr_, wi, ai); ai = fmaf(si_, wr, ai);
            float t = wr * stc - wi * sts; wi = wr * sts + wi * stc; wr = t;
        }
        // bottom run: ky = 48..63, start phase e^{2pi*i*48*y/64} = i^{(3y) mod 4} (exact)
        int q = (3 * y) & 3;
        float w2r = (q == 0) ? 1.f : ((q == 2) ? -1.f : 0.f);
        float w2i = (q == 1) ? 1.f : ((q == 3) ? -1.f : 0.f);
        for (int k = 16; k < 32; k++) {
            float sr_ = SR[k * 16 + kx], si_ = SI[k * 16 + kx];
            ar = fmaf(sr_, w2r, ar); ar = fmaf(-si_, w2i, ar);
            ai = fmaf(sr_, w2i, ai); ai = fmaf(si_, w2r, ai);
            float t = w2r * stc - w2i * sts; w2i = w2r * sts + w2i * stc; w2r = t;
        }
        GR[y * 16 + kx] = ar;
        GI[y * 16 + kx] = ai;
    }
    __syncthreads();
    // stage 2: over kx with c_kx weights (c2r semantics), + epilogue
    int x = tid & 63, ybase = tid >> 6;
    float cx, sx;
    __sincosf(STEP * (float)x, &sx, &cx);
    size_t mo = ((size_t)b * 64 + o) * HW;
    #pragma unroll
    for (int j = 0; j < 16; j++) {
        int y = ybase + 4 * j;
        float acc = GR[y * 16];   // kx = 0 term, weight 1, take Re
        float wr = cx, wi = sx;
        #pragma unroll
        for (int k = 1; k < 16; k++) {
            acc = fmaf(2.f * GR[y * 16 + k], wr, acc);
            acc = fmaf(-2.f * GI[y * 16 + k], wi, acc);
            float t = wr * cx - wi * sx; wi = wr * sx + wi * cx; wr = t;
        }
        float val = acc * (1.f / 64.f);
        int idx = y * 64 + x;
        if (is_h) {
            float pre = val + phbuf[mo + idx];
            float hh = (pre > 0.f) ? 1.0507009873554805f * pre
                                   : 1.7580993408473766f * (__expf(pre) - 1.f); // scale*alpha
            float z = zbuf[mo + idx];
            float hold = hbuf[mo + idx];
            hbuf[mo + idx] = (1.f - z) * hold + z * hh;
        } else if (g == 0) {
            float pre = val + zbuf[mo + idx];
            zbuf[mo + idx] = 1.f / (1.f + __expf(-pre));
        } else {
            float pre = val + rhbuf[mo + idx];
            float rr = 1.f / (1.f + __expf(-pre));
            rhbuf[mo + idx] = rr * hbuf[mo + idx];
        }
    }
}

extern "C" void kernel_launch(void* const* d_in, const int* in_sizes, int n_in,
                              void* d_out, int out_size, void* d_ws, size_t ws_size,
                              hipStream_t stream)
{
    (void)in_sizes; (void)n_in; (void)out_size; (void)ws_size;
    const float* x   = (const float*)d_in[0];
    const float* sw1 = (const float*)d_in[1];
    const float* sw2 = (const float*)d_in[2];
    const float* skw = (const float*)d_in[3];
    const float* gb  = (const float*)d_in[4];
    const float* bh  = (const float*)d_in[5];
    float* ws  = (float*)d_ws;
    float* Ux  = ws + OFF_UX;
    float* Uh  = ws + OFF_UH;
    float* Urh = ws + OFF_URH;
    float* Sp  = ws + OFF_SPART;
    float* hb  = ws + OFF_H;
    float* zb  = ws + OFF_Z;
    float* rhb = ws + OFF_RH;
    float* phb = ws + OFF_PH;

    const long long bs_x = (long long)TT_ * CC_ * HW;  // b-stride within x
    const long long bs_h = (long long)CC_ * HW;

    k_init_h<<<1024, 256, 0, stream>>>(hb, bh);
    for (int t = 0; t < TT_; t++) {
        const float* xt = x + (size_t)t * CC_ * HW;
        // spectra of xt and h
        k_fwd_dft2<<<512, 256, 0, stream>>>(xt, bs_x, Ux, hb, bs_h, Uh);
        // z & r spectral mixes (layers 0,1 and 2,3), i-chunk partials
        k_mix<<<512, 256, 0, stream>>>(Ux, Uh, 0, 1, 2, 3, sw1, sw2, Sp);
        // z & r skips + gate bias -> preactivations in zb / rhb
        k_skip2<<<512, 256, 0, stream>>>(xt, bs_x, hb, bs_h, skw,
                                         0, 1, 2, 3, gb, 0, 1, zb, rhb);
        // z = sigmoid(.), rh = sigmoid(.)*h
        k_idft<<<512, 256, 0, stream>>>(Sp, zb, rhb, hb, phb, 0);
        // spectrum of r*h
        k_fwd_dft2<<<256, 256, 0, stream>>>(rhb, bs_h, Urh, rhb, bs_h, Urh);
        // h_hat spectral mix (layers 4,5)
        k_mix<<<256, 256, 0, stream>>>(Ux, Urh, 4, 5, 4, 5, sw1, sw2, Sp);
        // h_hat skip -> phb
        k_skip2<<<256, 256, 0, stream>>>(xt, bs_x, rhb, bs_h, skw,
                                         4, 5, 4, 5, gb, 2, 2, phb, phb);
        // h = (1-z)h + z*selu(.)
        k_idft<<<256, 256, 0, stream>>>(Sp, zb, rhb, hb, phb, 1);
    }
    hipMemcpyAsync(d_out, hb, (size_t)BB_ * CC_ * HW * sizeof(float),
                   hipMemcpyDeviceToDevice, stream);
}

// Round 3
// 1016.044 us; speedup vs baseline: 1.5572x; 1.2122x over previous
//
#include <hip/hip_runtime.h>

#define BB_ 4
#define TT_ 8
#define CC_ 64
#define HW 4096
#define UMAP 1024      // floats per (b,c) spectrum map: 32 ky * 16 kx * 2
#define STEP 0.09817477042468103f   // 2*pi/64

// ws float offsets
#define OFF_UXALL 0                                     // 8*256*1024
#define OFF_UH    (OFF_UXALL + TT_*256*UMAP)            // 256*1024
#define OFF_URH   (OFF_UH + 256*UMAP)                   // 256*1024
#define OFF_SPART (OFF_URH + 256*UMAP)                  // 2 slots * 8 ic * 256 maps * 1024
#define OFF_H     (OFF_SPART + 2*8*256*UMAP)
#define OFF_Z     (OFF_H + BB_*CC_*HW)
#define OFF_RH    (OFF_Z + BB_*CC_*HW)
#define OFF_PH    (OFF_RH + BB_*CC_*HW)

// ---------------- init: h = bias, Uh = spectrum of constant map ----------------
__global__ __launch_bounds__(256) void k_init(float* __restrict__ hb,
                                              float* __restrict__ Uh,
                                              const float* __restrict__ bias_h) {
    float v = bias_h[0];
    int blk = blockIdx.x;
    if (blk < 1024) {
        int idx = (blk * 256 + threadIdx.x) * 4;
        *(float4*)(hb + idx) = make_float4(v, v, v, v);
    } else {
        // spectrum of constant v map: only (ky=0,kx=0) = 4096*v/64 = 64*v
        int map = blk - 1024;
        float4 z = make_float4(0.f, 0.f, 0.f, 0.f);
        if (threadIdx.x == 0) z.x = 64.f * v;
        *(float4*)(Uh + (size_t)map * UMAP + threadIdx.x * 4) = z;
    }
}

// ---------------- forward partial DFT stages (input already in LDS su[64*65]) ----
__device__ __forceinline__ void dft_stages(const float* __restrict__ su,
                                           float* __restrict__ FxR, float* __restrict__ FxI,
                                           float* __restrict__ dst) {
    int tid = threadIdx.x;
    // stage 1: along x. thread -> kx = tid&15, 4 y's
    int kx = tid & 15, yb = tid >> 4;
    float stc, sts;
    __sincosf(-STEP * (float)kx, &sts, &stc);
    float wr = 1.f, wi = 0.f;
    float aR[4] = {0, 0, 0, 0}, aI[4] = {0, 0, 0, 0};
    for (int x = 0; x < 64; x++) {
        #pragma unroll
        for (int j = 0; j < 4; j++) {
            float v = su[(yb + 16 * j) * 65 + x];
            aR[j] = fmaf(v, wr, aR[j]);
            aI[j] = fmaf(v, wi, aI[j]);
        }
        float t = wr * stc - wi * sts;
        wi = wr * sts + wi * stc;
        wr = t;
    }
    #pragma unroll
    for (int j = 0; j < 4; j++) {
        FxR[(yb + 16 * j) * 16 + kx] = aR[j];
        FxI[(yb + 16 * j) * 16 + kx] = aI[j];
    }
    __syncthreads();
    // stage 2: along y. thread -> kx, two ky (kb and kb+48)
    int kb = tid >> 4;
    float c0, s0, c1, s1;
    __sincosf(-STEP * (float)kb, &s0, &c0);
    __sincosf(-STEP * (float)(kb + 48), &s1, &c1);
    float w0r = 1, w0i = 0, w1r = 1, w1i = 0;
    float A0r = 0, A0i = 0, A1r = 0, A1i = 0;
    for (int y = 0; y < 64; y++) {
        float Fr = FxR[y * 16 + kx], Fi = FxI[y * 16 + kx];
        A0r = fmaf(Fr, w0r, A0r); A0r = fmaf(-Fi, w0i, A0r);
        A0i = fmaf(Fr, w0i, A0i); A0i = fmaf(Fi, w0r, A0i);
        A1r = fmaf(Fr, w1r, A1r); A1r = fmaf(-Fi, w1i, A1r);
        A1i = fmaf(Fr, w1i, A1i); A1i = fmaf(Fi, w1r, A1i);
        float t0 = w0r * c0 - w0i * s0; w0i = w0r * s0 + w0i * c0; w0r = t0;
        float t1 = w1r * c1 - w1i * s1; w1i = w1r * s1 + w1i * c1; w1r = t1;
    }
    const float sc = 1.f / 64.f;
    float2* d2 = (float2*)dst;
    d2[kb * 16 + kx]        = make_float2(A0r * sc, A0i * sc);
    d2[(kb + 16) * 16 + kx] = make_float2(A1r * sc, A1i * sc);
}

// ---------------- batched DFT of all x_t maps (once per launch) ----------------
__global__ __launch_bounds__(256) void k_dft_x(const float* __restrict__ x,
                                               float* __restrict__ Uxall) {
    __shared__ float su[64 * 65];
    __shared__ float FxR[1024], FxI[1024];
    int blk = blockIdx.x;
    int t = blk >> 8, map = blk & 255;
    int b = map >> 6, c = map & 63;
    const float* src = x + (((size_t)b * TT_ + t) * CC_ + c) * HW;
    int tid = threadIdx.x;
    #pragma unroll
    for (int k = 0; k < 4; k++) {
        int off = k * 1024 + tid * 4;
        float4 v = *(const float4*)(src + off);
        int y = off >> 6, xx = off & 63;
        su[y * 65 + xx + 0] = v.x; su[y * 65 + xx + 1] = v.y;
        su[y * 65 + xx + 2] = v.z; su[y * 65 + xx + 3] = v.w;
    }
    __syncthreads();
    dft_stages(su, FxR, FxI, Uxall + ((size_t)t * 256 + map) * UMAP);
}

// ---------------- per-mode channel mix (4 o per block, 8-i chunks) -------------
// blk bits: [g][half][ic(8)][og(16)]; thread m = mode within half (256).
// Spart layout: [((slot*8+ic)*256 + b*64+o)][UMAP], slot = g.
__device__ __forceinline__ void mix_body(int blk,
    const float* __restrict__ UA, const float* __restrict__ UB,
    int lA0, int lB0, int lA1, int lB1,
    const float* __restrict__ sw1, const float* __restrict__ sw2,
    float* __restrict__ Spart)
{
    int og = blk & 15;
    int ic = (blk >> 4) & 7;
    int half = (blk >> 7) & 1;
    int g = (blk >> 8) & 1;
    int m = threadIdx.x;
    int o0 = og * 4, ib = ic * 8;
    int lA = g ? lA1 : lA0;
    int lB = g ? lB1 : lB0;
    const float2* wt = (const float2*)(half ? sw2 : sw1);
    float aR[4][4], aI[4][4];
    #pragma unroll
    for (int oo = 0; oo < 4; oo++)
        #pragma unroll
        for (int b = 0; b < 4; b++) { aR[oo][b] = 0.f; aI[oo][b] = 0.f; }
    #pragma unroll
    for (int p = 0; p < 2; p++) {
        int l = p ? lB : lA;
        const float2* U2 = (const float2*)(p ? UB : UA) + ((size_t)ib * 512 + half * 256 + m);
        const float2* W2 = wt + (((size_t)l * 64 + ib) * 64 + o0) * 256 + m;
        for (int ii = 0; ii < 8; ii++) {
            float2 w0 = W2[0], w1 = W2[256], w2 = W2[512], w3 = W2[768];
            W2 += 16384;
            const float2* up = U2 + (size_t)ii * 512;
            #pragma unroll
            for (int b = 0; b < 4; b++) {
                float2 u = up[(size_t)b * 32768];
                aR[0][b] = fmaf(u.x, w0.x, aR[0][b]); aR[0][b] = fmaf(-u.y, w0.y, aR[0][b]);
                aI[0][b] = fmaf(u.x, w0.y, aI[0][b]); aI[0][b] = fmaf(u.y, w0.x, aI[0][b]);
                aR[1][b] = fmaf(u.x, w1.x, aR[1][b]); aR[1][b] = fmaf(-u.y, w1.y, aR[1][b]);
                aI[1][b] = fmaf(u.x, w1.y, aI[1][b]); aI[1][b] = fmaf(u.y, w1.x, aI[1][b]);
                aR[2][b] = fmaf(u.x, w2.x, aR[2][b]); aR[2][b] = fmaf(-u.y, w2.y, aR[2][b]);
                aI[2][b] = fmaf(u.x, w2.y, aI[2][b]); aI[2][b] = fmaf(u.y, w2.x, aI[2][b]);
                aR[3][b] = fmaf(u.x, w3.x, aR[3][b]); aR[3][b] = fmaf(-u.y, w3.y, aR[3][b]);
                aI[3][b] = fmaf(u.x, w3.y, aI[3][b]); aI[3][b] = fmaf(u.y, w3.x, aI[3][b]);
            }
        }
    }
    float2* S2 = (float2*)Spart;
    #pragma unroll
    for (int oo = 0; oo < 4; oo++)
        #pragma unroll
        for (int b = 0; b < 4; b++)
            S2[((size_t)(g * 8 + ic) * 256 + b * 64 + o0 + oo) * 512 + half * 256 + m]
                = make_float2(aR[oo][b], aI[oo][b]);
}

// ---------------- 1x1-conv skip (shared-body) ----------------------------------
__device__ __forceinline__ void skip_body(int blk, float* sA, float* sB,
    const float* __restrict__ uA, long long bsA,
    const float* __restrict__ uB, long long bsB,
    const float* __restrict__ skw,
    int lA0, int lB0, int lA1, int lB1,
    const float* __restrict__ gate_b, int g0, int g1,
    float* __restrict__ out0, float* __restrict__ out1)
{
    int g = blk >> 8;
    int r = blk & 255;
    int b = r >> 6, tile = r & 63;
    int tid = threadIdx.x;
    int o = tid & 63, wv = tid >> 6;
    int pxb = tile * 64 + wv * 16;
    int lA = g ? lA1 : lA0;
    int lB = g ? lB1 : lB0;
    for (int n = 0; n < 16; n++) {
        int idx = n * 256 + tid;
        sA[idx] = skw[lA * 4096 + idx];
        sB[idx] = skw[lB * 4096 + idx];
    }
    __syncthreads();
    float acc[16];
    #pragma unroll
    for (int k = 0; k < 16; k++) acc[k] = 0.f;
    const float* pa = uA + (long long)b * bsA + pxb;
    const float* pb = uB + (long long)b * bsB + pxb;
    for (int i = 0; i < 64; i++) {
        float wa = sA[i * 64 + o];
        float wb2 = sB[i * 64 + o];
        const float4* qa = (const float4*)(pa + i * HW);
        const float4* qb = (const float4*)(pb + i * HW);
        #pragma unroll
        for (int q = 0; q < 4; q++) {
            float4 va = qa[q], vb = qb[q];
            acc[4 * q + 0] = fmaf(wa, va.x, acc[4 * q + 0]);
            acc[4 * q + 0] = fmaf(wb2, vb.x, acc[4 * q + 0]);
            acc[4 * q + 1] = fmaf(wa, va.y, acc[4 * q + 1]);
            acc[4 * q + 1] = fmaf(wb2, vb.y, acc[4 * q + 1]);
            acc[4 * q + 2] = fmaf(wa, va.z, acc[4 * q + 2]);
            acc[4 * q + 2] = fmaf(wb2, vb.z, acc[4 * q + 2]);
            acc[4 * q + 3] = fmaf(wa, va.w, acc[4 * q + 3]);
            acc[4 * q + 3] = fmaf(wb2, vb.w, acc[4 * q + 3]);
        }
    }
    float gb = gate_b[g ? g1 : g0];
    float* outp = (g ? out1 : out0) + ((long long)b * 64 + o) * HW + pxb;
    #pragma unroll
    for (int k = 0; k < 16; k++) outp[k] = acc[k] + gb;
}

// ---------------- fused front kernels: mix + skip -------------------------------
__global__ __launch_bounds__(256) void k_front_zr(
    const float* __restrict__ Uxt, const float* __restrict__ Uh,
    const float* __restrict__ xt, const float* __restrict__ hb,
    const float* __restrict__ sw1, const float* __restrict__ sw2,
    const float* __restrict__ skw, const float* __restrict__ gate_b,
    float* __restrict__ Spart, float* __restrict__ zb, float* __restrict__ rhb)
{
    __shared__ float smem[8192];
    int blk = blockIdx.x;
    if (blk < 512) {
        mix_body(blk, Uxt, Uh, 0, 1, 2, 3, sw1, sw2, Spart);
    } else {
        skip_body(blk - 512, smem, smem + 4096,
                  xt, (long long)TT_ * CC_ * HW, hb, (long long)CC_ * HW,
                  skw, 0, 1, 2, 3, gate_b, 0, 1, zb, rhb);
    }
}

__global__ __launch_bounds__(256) void k_front_h(
    const float* __restrict__ Uxt, const float* __restrict__ Urh,
    const float* __restrict__ xt, const float* __restrict__ rhb,
    const float* __restrict__ sw1, const float* __restrict__ sw2,
    const float* __restrict__ skw, const float* __restrict__ gate_b,
    float* __restrict__ Spart, float* __restrict__ phb)
{
    __shared__ float smem[8192];
    int blk = blockIdx.x;
    if (blk < 256) {
        mix_body(blk, Uxt, Urh, 4, 5, 4, 5, sw1, sw2, Spart);
    } else {
        skip_body(blk - 256, smem, smem + 4096,
                  xt, (long long)TT_ * CC_ * HW, rhb, (long long)CC_ * HW,
                  skw, 4, 5, 4, 5, gate_b, 2, 2, phb, phb);
    }
}

// ---------------- inverse DFT stage 1 (shared) ----------------------------------
__device__ __forceinline__ void idft_stage1(const float* __restrict__ SR,
                                            const float* __restrict__ SI,
                                            float* __restrict__ GR, float* __restrict__ GI)
{
    int tid = threadIdx.x;
    int kx = tid & 15, yb = tid >> 4;
    #pragma unroll
    for (int j = 0; j < 4; j++) {
        int y = yb + 16 * j;
        float stc, sts;
        __sincosf(STEP * (float)y, &sts, &stc);
        float ar = 0.f, ai = 0.f;
        float wr = 1.f, wi = 0.f;
        for (int k = 0; k < 16; k++) {
            float sr_ = SR[k * 16 + kx], si_ = SI[k * 16 + kx];
            ar = fmaf(sr_, wr, ar); ar = fmaf(-si_, wi, ar);
            ai = fmaf(sr_, wi, ai); ai = fmaf(si_, wr, ai);
            float t = wr * stc - wi * sts; wi = wr * sts + wi * stc; wr = t;
        }
        int q = (3 * y) & 3;
        float w2r = (q == 0) ? 1.f : ((q == 2) ? -1.f : 0.f);
        float w2i = (q == 1) ? 1.f : ((q == 3) ? -1.f : 0.f);
        for (int k = 16; k < 32; k++) {
            float sr_ = SR[k * 16 + kx], si_ = SI[k * 16 + kx];
            ar = fmaf(sr_, w2r, ar); ar = fmaf(-si_, w2i, ar);
            ai = fmaf(sr_, w2i, ai); ai = fmaf(si_, w2r, ai);
            float t = w2r * stc - w2i * sts; w2i = w2r * sts + w2i * stc; w2r = t;
        }
        GR[y * 16 + kx] = ar;
        GI[y * 16 + kx] = ai;
    }
}

// ---------------- back kernel zr: idft + gate epilogue + fused rh forward DFT ---
__global__ __launch_bounds__(256) void k_back_zr(
    const float* __restrict__ Spart,
    float* __restrict__ zb, float* __restrict__ rhb,
    const float* __restrict__ hb, float* __restrict__ Urh)
{
    __shared__ float smem[6208];
    float* SR = smem;          // 512
    float* SI = smem + 512;    // 512
    float* GR = smem + 1024;   // 1024
    float* GI = smem + 2048;   // 1024
    int g = blockIdx.x >> 8;
    int map = blockIdx.x & 255;
    int tid = threadIdx.x;
    {
        const float4* base = (const float4*)Spart;
        float sxr = 0, sxi = 0, syr = 0, syi = 0;
        #pragma unroll
        for (int ic = 0; ic < 8; ic++) {
            float4 v = base[((size_t)(g * 8 + ic) * 256 + map) * 256 + tid];
            sxr += v.x; sxi += v.y; syr += v.z; syi += v.w;
        }
        SR[2 * tid] = sxr; SI[2 * tid] = sxi;
        SR[2 * tid + 1] = syr; SI[2 * tid + 1] = syi;
    }
    __syncthreads();
    idft_stage1(SR, SI, GR, GI);
    __syncthreads();
    int x = tid & 63, ybase = tid >> 6;
    float cx, sx;
    __sincosf(STEP * (float)x, &sx, &cx);
    size_t mo = (size_t)map * HW;
    float rhv[16];
    #pragma unroll
    for (int j = 0; j < 16; j++) {
        int y = ybase + 4 * j;
        float acc = GR[y * 16];
        float wr = cx, wi = sx;
        #pragma unroll
        for (int k = 1; k < 16; k++) {
            acc = fmaf(2.f * GR[y * 16 + k], wr, acc);
            acc = fmaf(-2.f * GI[y * 16 + k], wi, acc);
            float t = wr * cx - wi * sx; wi = wr * sx + wi * cx; wr = t;
        }
        float val = acc * (1.f / 64.f);
        int idx = y * 64 + x;
        if (g == 0) {
            float pre = val + zb[mo + idx];
            zb[mo + idx] = 1.f / (1.f + __expf(-pre));
        } else {
            float pre = val + rhb[mo + idx];
            float rr = 1.f / (1.f + __expf(-pre));
            float rh = rr * hb[mo + idx];
            rhb[mo + idx] = rh;
            rhv[j] = rh;
        }
    }
    if (g == 0) return;
    // rh map -> in-block forward DFT -> Urh
    __syncthreads();                 // all GR/GI reads done before overwrite
    float* su = smem;                // 4160 floats (overlays SR/SI/GR/GI)
    #pragma unroll
    for (int j = 0; j < 16; j++) {
        int y = ybase + 4 * j;
        su[y * 65 + x] = rhv[j];
    }
    __syncthreads();
    dft_stages(su, smem + 4160, smem + 5184, Urh + (size_t)map * UMAP);
}

// ---------------- back kernel h: idft + GRU update + fused h forward DFT --------
__global__ __launch_bounds__(256) void k_back_h(
    const float* __restrict__ Spart,
    const float* __restrict__ zb, const float* __restrict__ phb,
    float* __restrict__ hb, float* __restrict__ Uh)
{
    __shared__ float smem[6208];
    float* SR = smem;
    float* SI = smem + 512;
    float* GR = smem + 1024;
    float* GI = smem + 2048;
    int map = blockIdx.x & 255;
    int tid = threadIdx.x;
    {
        const float4* base = (const float4*)Spart;
        float sxr = 0, sxi = 0, syr = 0, syi = 0;
        #pragma unroll
        for (int ic = 0; ic < 8; ic++) {
            float4 v = base[((size_t)ic * 256 + map) * 256 + tid];
            sxr += v.x; sxi += v.y; syr += v.z; syi += v.w;
        }
        SR[2 * tid] = sxr; SI[2 * tid] = sxi;
        SR[2 * tid + 1] = syr; SI[2 * tid + 1] = syi;
    }
    __syncthreads();
    idft_stage1(SR, SI, GR, GI);
    __syncthreads();
    int x = tid & 63, ybase = tid >> 6;
    float cx, sx;
    __sincosf(STEP * (float)x, &sx, &cx);
    size_t mo = (size_t)map * HW;
    float hv[16];
    #pragma unroll
    for (int j = 0; j < 16; j++) {
        int y = ybase + 4 * j;
        float acc = GR[y * 16];
        float wr = cx, wi = sx;
        #pragma unroll
        for (int k = 1; k < 16; k++) {
            acc = fmaf(2.f * GR[y * 16 + k], wr, acc);
            acc = fmaf(-2.f * GI[y * 16 + k], wi, acc);
            float t = wr * cx - wi * sx; wi = wr * sx + wi * cx; wr = t;
        }
        float val = acc * (1.f / 64.f);
        int idx = y * 64 + x;
        float pre = val + phb[mo + idx];
        float hh = (pre > 0.f) ? 1.0507009873554805f * pre
                               : 1.7580993408473766f * (__expf(pre) - 1.f);
        float z = zb[mo + idx];
        float hn = fmaf(z, hh - hb[mo + idx], hb[mo + idx]);  // (1-z)h + z*hh
        hb[mo + idx] = hn;
        hv[j] = hn;
    }
    // new h map -> in-block forward DFT -> Uh (for next step's mix)
    __syncthreads();
    float* su = smem;
    #pragma unroll
    for (int j = 0; j < 16; j++) {
        int y = ybase + 4 * j;
        su[y * 65 + x] = hv[j];
    }
    __syncthreads();
    dft_stages(su, smem + 4160, smem + 5184, Uh + (size_t)map * UMAP);
}

extern "C" void kernel_launch(void* const* d_in, const int* in_sizes, int n_in,
                              void* d_out, int out_size, void* d_ws, size_t ws_size,
                              hipStream_t stream)
{
    (void)in_sizes; (void)n_in; (void)out_size; (void)ws_size;
    const float* x   = (const float*)d_in[0];
    const float* sw1 = (const float*)d_in[1];
    const float* sw2 = (const float*)d_in[2];
    const float* skw = (const float*)d_in[3];
    const float* gb  = (const float*)d_in[4];
    const float* bh  = (const float*)d_in[5];
    float* ws    = (float*)d_ws;
    float* Uxall = ws + OFF_UXALL;
    float* Uh    = ws + OFF_UH;
    float* Urh   = ws + OFF_URH;
    float* Sp    = ws + OFF_SPART;
    float* hb    = ws + OFF_H;
    float* zb    = ws + OFF_Z;
    float* rhb   = ws + OFF_RH;
    float* phb   = ws + OFF_PH;

    k_init<<<1280, 256, 0, stream>>>(hb, Uh, bh);
    k_dft_x<<<2048, 256, 0, stream>>>(x, Uxall);
    for (int t = 0; t < TT_; t++) {
        const float* xt  = x + (size_t)t * CC_ * HW;
        const float* Uxt = Uxall + (size_t)t * 256 * UMAP;
        k_front_zr<<<1024, 256, 0, stream>>>(Uxt, Uh, xt, hb, sw1, sw2, skw, gb,
                                             Sp, zb, rhb);
        k_back_zr<<<512, 256, 0, stream>>>(Sp, zb, rhb, hb, Urh);
        k_front_h<<<512, 256, 0, stream>>>(Uxt, Urh, xt, rhb, sw1, sw2, skw, gb,
                                           Sp, phb);
        k_back_h<<<256, 256, 0, stream>>>(Sp, zb, phb, hb, Uh);
    }
    hipMemcpyAsync(d_out, hb, (size_t)BB_ * CC_ * HW * sizeof(float),
                   hipMemcpyDeviceToDevice, stream);
}